// Round 8
// baseline (665.540 us; speedup 1.0000x reference)
//
#include <hip/hip_runtime.h>

#define N_ 32
#define C_ 512
#define T_ 2048
#define K_ 1024
#define NT_ 65536
#define EPS_ 0.12f

typedef _Float16 f16;
typedef f16 f16x2 __attribute__((ext_vector_type(2)));
typedef f16 f16x4 __attribute__((ext_vector_type(4)));
typedef f16 f16x8 __attribute__((ext_vector_type(8)));
typedef float f32x4 __attribute__((ext_vector_type(4)));

// ---- ws layout (bytes) ----
#define OFF_CBH  ((size_t)0)          // f16 cb, tiled [8 kblk][16 co][128 k][32 c]  (1 MB)
#define OFF_KN   ((size_t)1048576)    // fp32 knorm [1024]
#define OFF_CNT  ((size_t)1052672)    // int count (zeroed by knorm_init)
#define OFF_LST  ((size_t)1052928)    // int worklist [65536]
#define WS_NEED  ((size_t)1315072)

#define GLOAD(g, l) __builtin_amdgcn_global_load_lds( \
    (__attribute__((address_space(1))) const unsigned int*)(const void*)(g), \
    (__attribute__((address_space(3))) unsigned int*)(void*)(l), 16, 0, 0)

// ---------------- Kernel 1: codebook norms + zero scalars + zero worklist count ----------------
__global__ void knorm_init_kernel(const float* __restrict__ cb,
                                  float* __restrict__ knorm,
                                  float* __restrict__ out,
                                  int* __restrict__ cnt) {
    const int k = blockIdx.x;
    const int lane = threadIdx.x;
    const float* row = cb + (size_t)k * C_;
    float s = 0.f;
#pragma unroll
    for (int j = 0; j < C_ / 64; ++j) {
        float v = row[lane + 64 * j];
        s += v * v;
    }
#pragma unroll
    for (int off = 32; off > 0; off >>= 1) s += __shfl_down(s, off, 64);
    if (lane == 0) knorm[k] = s;
    if (k == 0 && lane == 0) {
        out[(size_t)N_ * C_ * T_ + 0] = 0.f;
        out[(size_t)N_ * C_ * T_ + 1] = 0.f;
        *cnt = 0;
    }
}

// ---------------- Kernel 2: convert codebook to tiled f16 ----------------
__global__ void __launch_bounds__(256) conv_cb_kernel(const float* __restrict__ cb,
                                                      f16* __restrict__ cbws) {
    const int tid = threadIdx.x;
    const int kblk = blockIdx.x >> 4;
    const int co = blockIdx.x & 15;
    const float* src = cb + (size_t)kblk * 128 * C_ + co * 32;
    f16* dst = cbws + (size_t)kblk * 65536 + (size_t)co * 4096;
#pragma unroll
    for (int j = 0; j < 4; ++j) {
        int f = tid + 256 * j;            // 0..1023
        int k_l = f >> 3;                 // 0..127
        int c4 = (f & 7) * 4;             // 0..28
        float4 v = *(const float4*)(src + (size_t)k_l * C_ + c4);
        f16x4 h = {(f16)v.x, (f16)v.y, (f16)v.z, (f16)v.w};
        *(f16x4*)(dst + (size_t)k_l * 32 + c4) = h;
    }
}

// ---------------- Kernel 3: FUSED transpose + A-resident MFMA + top2 + gather ----------------
// One block per 128-t tile (512 blocks x 256 thr, 1 block/CU, 155KB LDS).
// Phase A: transpose x fp32 -> f16 A-tile IN LDS (128KB, chunk-swizzled layout,
//          conv_x's verified scratch pattern). A is then read-only for the kernel.
// Phase B: 128 phases (8 kblk x 16 co) staging ONLY B (8KB/phase, L2-resident cbws)
//          via R4-verified dbuf GLOAD swizzle; R4 wave geometry (4x 64t*64k, acc[4][4]).
// Per-kblk top2 fold (R7-verified) -> worklist append + fused gather (R7-verified).
__global__ void __launch_bounds__(256, 1)
vq_fused2_kernel(const float* __restrict__ x, const float* __restrict__ cb,
                 const f16* __restrict__ cbws, const float* __restrict__ knorm,
                 float* __restrict__ out, int* __restrict__ cnt, int* __restrict__ list) {
    // LDS map (bytes):
    //   [0,      131072)  A tile [16 co][128 t][64 B/row], chunk-swizzled
    //   [131072, 147456)  B dbuf 2 x 8192   (transpose scratch overlays first 8704 B)
    //   [147456, 151552)  kns 1024 f32
    //   [151552, 154624)  mrg 768 f32
    //   [154624, 155136)  idxs 128 int
    __shared__ __align__(16) char smem[155136];
    char* Abase = smem;
    char* Bbase = smem + 131072;
    float* kns = (float*)(smem + 147456);
    float* mrg = (float*)(smem + 151552);
    int* idxs = (int*)(smem + 154624);
    f16* trans = (f16*)(smem + 131072);   // scratch during transpose only

    const int tid = threadIdx.x;
    const int lane = tid & 63, w = tid >> 6;
    const int wy = w >> 1, wx = w & 1;
    const int col = lane & 15, quad = lane >> 4;
    const int tblk = blockIdx.x;              // 0..511
    const int n = tblk >> 4;
    const int t0 = (tblk & 15) << 7;

    // ---------- transpose x -> A (conv_x's verified pattern + swizzled A-write) ----------
    // A write layout: byte = co*8192 + t*64 + ((chunk ^ ((t>>1)&3))<<4) + inchunk,
    // matching the GLOAD-staged layout the R4 read formula expects.
    const float* xb = x + (size_t)n * C_ * T_ + t0;
    const int cp = tid >> 5;
    const int s = tid & 31;
    for (int co = 0; co < 16; ++co) {
        __syncthreads();                      // scratch reuse across slabs
#pragma unroll
        for (int j = 0; j < 2; ++j) {
            int c0 = (cp + 8 * j) * 2;
            float4 v0 = *(const float4*)(xb + (size_t)(co * 32 + c0) * T_ + s * 4);
            float4 v1 = *(const float4*)(xb + (size_t)(co * 32 + c0 + 1) * T_ + s * 4);
            f16x2 w0 = {(f16)v0.x, (f16)v1.x};
            f16x2 w1 = {(f16)v0.y, (f16)v1.y};
            f16x2 w2 = {(f16)v0.z, (f16)v1.z};
            f16x2 w3 = {(f16)v0.w, (f16)v1.w};
            *(f16x2*)&trans[(s * 4 + 0) * 34 + c0] = w0;
            *(f16x2*)&trans[(s * 4 + 1) * 34 + c0] = w1;
            *(f16x2*)&trans[(s * 4 + 2) * 34 + c0] = w2;
            *(f16x2*)&trans[(s * 4 + 3) * 34 + c0] = w3;
        }
        __syncthreads();
#pragma unroll
        for (int j = 0; j < 8; ++j) {
            int p = tid + 256 * j;
            int t_l = p >> 4;
            int cpo = p & 15;
            f16x2 v = *(const f16x2*)&trans[t_l * 34 + cpo * 2];
            *(f16x2*)(Abase + co * 8192 + t_l * 64 +
                      ((((cpo >> 2) ^ ((t_l >> 1) & 3)) << 4)) + (cpo & 3) * 4) = v;
        }
    }
    __syncthreads();                          // all trans reads done; B region now free

    // kns + B prologue
    kns[tid] = knorm[tid];
    kns[tid + 256] = knorm[tid + 256];
    kns[tid + 512] = knorm[tid + 512];
    kns[tid + 768] = knorm[tid + 768];

    // B staging (R4-verified source-side chunk swizzle; 4 waves x 2 GLOADs = 8KB)
    const int swz = ((lane >> 2) << 6) + (((lane & 3) ^ ((lane >> 3) & 3)) << 4);
    const char* gB = (const char*)cbws + w * 2048 + swz;

    // read offsets (R4-verified): chunk = quad ^ ((col>>1)&3)
    const int rchunk = (quad ^ ((col >> 1) & 3)) * 8;   // f16 units
    const int abase_[4] = {(wy * 64 + 0 * 16 + col) * 32 + rchunk,
                           (wy * 64 + 1 * 16 + col) * 32 + rchunk,
                           (wy * 64 + 2 * 16 + col) * 32 + rchunk,
                           (wy * 64 + 3 * 16 + col) * 32 + rchunk};
    const int boff[4] = {(wx * 64 + 0 * 16 + col) * 32 + rchunk,
                         (wx * 64 + 1 * 16 + col) * 32 + rchunk,
                         (wx * 64 + 2 * 16 + col) * 32 + rchunk,
                         (wx * 64 + 3 * 16 + col) * 32 + rchunk};

    GLOAD(gB, Bbase + w * 2048);              // stage phase 0 into buf0
    GLOAD(gB + 1024, Bbase + w * 2048 + 1024);
    __syncthreads();                          // phase 0 landed; kns visible

    float rv1f = 3.4e38f, rv2f = 3.4e38f;     // running top2 (meaningful in tid<128)
    int ri1f = 0;
    int cur = 0;

    for (int kblk = 0; kblk < 8; ++kblk) {
        f32x4 acc[4][4];
#pragma unroll
        for (int i = 0; i < 4; ++i)
#pragma unroll
            for (int j = 0; j < 4; ++j) acc[i][j] = (f32x4){0.f, 0.f, 0.f, 0.f};

        for (int co = 0; co < 16; ++co) {
            const int p = kblk * 16 + co;
            if (p < 127) {                     // prefetch next B phase into other buffer
                const char* gBn = (const char*)cbws + (size_t)(p + 1) * 8192 + w * 2048 + swz;
                char* ln = Bbase + (cur ^ 1) * 8192 + w * 2048;
                GLOAD(gBn, ln);
                GLOAD(gBn + 1024, ln + 1024);
            }
            const f16* As = (const f16*)(Abase + co * 8192);
            const f16* Bs = (const f16*)(Bbase + cur * 8192);
            f16x8 af[4], bf[4];
#pragma unroll
            for (int ti = 0; ti < 4; ++ti) af[ti] = *(const f16x8*)(As + abase_[ti]);
#pragma unroll
            for (int ki = 0; ki < 4; ++ki) bf[ki] = *(const f16x8*)(Bs + boff[ki]);
#pragma unroll
            for (int ti = 0; ti < 4; ++ti)
#pragma unroll
                for (int ki = 0; ki < 4; ++ki)
                    acc[ti][ki] = __builtin_amdgcn_mfma_f32_16x16x32_f16(af[ti], bf[ki], acc[ti][ki], 0, 0, 0);
            __syncthreads();                   // drains prefetch; protects B buf reuse
            cur ^= 1;
        }

        // ---- per-kblk top2 -> mrg -> fold into running (R7-verified) ----
#pragma unroll
        for (int ti = 0; ti < 4; ++ti) {
#pragma unroll
            for (int reg = 0; reg < 4; ++reg) {
                float rv1 = 3.4e38f, rv2 = 3.4e38f;
                int ri1 = 0;
#pragma unroll
                for (int ki = 0; ki < 4; ++ki) {
                    int kl = wx * 64 + ki * 16 + col;
                    float sc = fmaf(-2.f, acc[ti][ki][reg], kns[kblk * 128 + kl]);
                    int kg = kblk * 128 + kl;
                    if (sc < rv1) { rv2 = rv1; rv1 = sc; ri1 = kg; }
                    else if (sc < rv2) rv2 = sc;
                }
#pragma unroll
                for (int m = 1; m <= 8; m <<= 1) {
                    float ov1 = __shfl_xor(rv1, m, 64);
                    float ov2 = __shfl_xor(rv2, m, 64);
                    int oi1 = __shfl_xor(ri1, m, 64);
                    float nv2 = fminf(fminf(rv2, ov2), fmaxf(rv1, ov1));
                    if (ov1 < rv1 || (ov1 == rv1 && oi1 < ri1)) { rv1 = ov1; ri1 = oi1; }
                    rv2 = nv2;
                }
                if (col == 0) {
                    int t_l = wy * 64 + ti * 16 + quad * 4 + reg;
                    float* pp = &mrg[(t_l * 2 + wx) * 3];
                    pp[0] = rv1; pp[1] = __int_as_float(ri1); pp[2] = rv2;
                }
            }
        }
        __syncthreads();
        if (tid < 128) {
            const float* pa = &mrg[tid * 6];
            const float* pb = &mrg[tid * 6 + 3];
            float v1 = pa[0], v2 = pa[2];
            int i1 = __float_as_int(pa[1]);
            float ov1 = pb[0], ov2 = pb[2];
            int oi1 = __float_as_int(pb[1]);
            float nv2 = fminf(fminf(v2, ov2), fmaxf(v1, ov1));
            if (ov1 < v1 || (ov1 == v1 && oi1 < i1)) { v1 = ov1; i1 = oi1; }
            float fv2 = fminf(fminf(rv2f, nv2), fmaxf(rv1f, v1));
            if (v1 < rv1f || (v1 == rv1f && i1 < ri1f)) { rv1f = v1; ri1f = i1; }
            rv2f = fv2;
        }
        __syncthreads();                       // mrg reuse next kblk
    }

    // ---------- epilogue: worklist append + fused gather (R7-verified) ----------
    if (tid < 128) {
        if (rv2f <= rv1f + 2.f * EPS_) {
            int p = atomicAdd(cnt, 1);
            list[p] = tblk * 128 + tid;
        }
        idxs[tid] = ri1f;
    }
    __syncthreads();
    const int tg = (tid & 31) * 4;
    const int cs = tid >> 5;
    const float* r0 = cb + (size_t)idxs[tg + 0] * C_;
    const float* r1 = cb + (size_t)idxs[tg + 1] * C_;
    const float* r2 = cb + (size_t)idxs[tg + 2] * C_;
    const float* r3 = cb + (size_t)idxs[tg + 3] * C_;
    float* obase = out + (size_t)n * C_ * T_ + t0 + tg;
    for (int c = cs; c < C_; c += 8) {
        float4 v;
        v.x = r0[c]; v.y = r1[c]; v.z = r2[c]; v.w = r3[c];
        *(float4*)&obase[(size_t)c * T_] = v;
    }
}

// ---------------- Kernel 4: exact fp32 rescan + out rewrite (R6/R7-verified) ----------------
__global__ void __launch_bounds__(256) rescan3b_kernel(const float* __restrict__ x,
                                                       const float* __restrict__ cb,
                                                       const float* __restrict__ knorm,
                                                       const int* __restrict__ cnt,
                                                       const int* __restrict__ list,
                                                       float* __restrict__ out) {
    __shared__ __align__(16) f32x4 tile[4][512];   // 32KB: [c4][code ^ (c4<<1)]
    __shared__ __align__(16) float xs[4][512];     // 8KB
    __shared__ float redv[4][256];                 // 4KB
    __shared__ int redk[4][256];                   // 4KB
    const int tid = threadIdx.x;
    const int nf = *cnt;
    for (int base = blockIdx.x * 4; base < nf; base += gridDim.x * 4) {
        const int nr = (nf - base < 4) ? (nf - base) : 4;
        __syncthreads();   // protect xs/tile/redk reuse across grid-stride iterations
        for (int i = tid; i < nr * 512; i += 256) {
            int r = i >> 9, c = i & 511;
            int rr = list[base + r];
            int n = rr >> 11, t = rr & 2047;
            xs[r][c] = x[(size_t)n * C_ * T_ + (size_t)c * T_ + t];
        }

        float bv[4];
        int bk[4];
#pragma unroll
        for (int r = 0; r < 4; ++r) { bv[r] = 3.4e38f; bk[r] = 0; }

        for (int kpass = 0; kpass < 2; ++kpass) {
            float acc[2][4];   // [j(code)][item]
#pragma unroll
            for (int j = 0; j < 2; ++j)
#pragma unroll
                for (int r = 0; r < 4; ++r) acc[j][r] = 0.f;

            for (int cc = 0; cc < 32; ++cc) {      // 16-float c-chunks
                __syncthreads();
#pragma unroll
                for (int jj = 0; jj < 8; ++jj) {
                    int q = tid + 256 * jj;        // 0..2047
                    int row = q >> 2;              // 0..511
                    int c4 = q & 3;                // 0..3
                    f32x4 v = *(const f32x4*)(cb + (size_t)(kpass * 512 + row) * C_ + cc * 16 + c4 * 4);
                    tile[c4][row ^ (c4 << 1)] = v;
                }
                __syncthreads();
                f32x4 xv[4][4];
#pragma unroll
                for (int r = 0; r < 4; ++r)
#pragma unroll
                    for (int c4 = 0; c4 < 4; ++c4)
                        xv[r][c4] = *(const f32x4*)&xs[r][cc * 16 + c4 * 4];
#pragma unroll
                for (int j = 0; j < 2; ++j) {
                    int kl = tid + 256 * j;
#pragma unroll
                    for (int c4 = 0; c4 < 4; ++c4) {
                        f32x4 cv = tile[c4][kl ^ (c4 << 1)];
#pragma unroll
                        for (int r = 0; r < 4; ++r) {
                            acc[j][r] = fmaf(cv.x, xv[r][c4].x, acc[j][r]);
                            acc[j][r] = fmaf(cv.y, xv[r][c4].y, acc[j][r]);
                            acc[j][r] = fmaf(cv.z, xv[r][c4].z, acc[j][r]);
                            acc[j][r] = fmaf(cv.w, xv[r][c4].w, acc[j][r]);
                        }
                    }
                }
            }
#pragma unroll
            for (int j = 0; j < 2; ++j) {
                int k = kpass * 512 + tid + 256 * j;
                float kn = knorm[k];
#pragma unroll
                for (int r = 0; r < 4; ++r) {
                    float sc = fmaf(-2.f, acc[j][r], kn);
                    if (sc < bv[r]) { bv[r] = sc; bk[r] = k; }
                }
            }
        }
#pragma unroll
        for (int r = 0; r < 4; ++r) {
            redv[r][tid] = bv[r];
            redk[r][tid] = bk[r];
        }
        __syncthreads();
        for (int off = 128; off > 0; off >>= 1) {
            if (tid < off) {
#pragma unroll
                for (int r = 0; r < 4; ++r) {
                    float ov = redv[r][tid + off];
                    int ok = redk[r][tid + off];
                    if (ov < redv[r][tid] || (ov == redv[r][tid] && ok < redk[r][tid])) {
                        redv[r][tid] = ov;
                        redk[r][tid] = ok;
                    }
                }
            }
            __syncthreads();
        }
        // rewrite out rows with the exact winner (overwrites vq_fused2's approx row)
        for (int i = tid; i < nr * 512; i += 256) {
            int r = i >> 9, c = i & 511;
            int rr = list[base + r];
            int n = rr >> 11, t = rr & 2047;
            out[(size_t)n * C_ * T_ + (size_t)c * T_ + t] = cb[(size_t)redk[r][0] * C_ + c];
        }
    }
}

// ---------------- Fallback (round-1 fp32 path, verified correct) ----------------
__global__ void __launch_bounds__(256)
vq_fallback_kernel(const float* __restrict__ x, const float* __restrict__ cb,
                   const float* __restrict__ knorm, float* __restrict__ out) {
    __shared__ float smem[4416];
    float* Xs = smem;
    float* Bs = smem + 2048;
    float* kns = smem + 4160;
    int* idxs = (int*)(smem + 4288);
    float* redv = smem;
    int* redk = (int*)(smem + 2048);

    const int tid = threadIdx.x;
    const int tx = tid & 15;
    const int ty = tid >> 4;
    const int b = blockIdx.x;
    const int n = b >> 4;
    const int t0 = (b & 15) * 128;
    const float* xbase = x + (size_t)n * C_ * T_ + t0;

    float best[8];
    int bestk[8];
#pragma unroll
    for (int i = 0; i < 8; ++i) { best[i] = 3.4e38f; bestk[i] = 0; }

    for (int k0 = 0; k0 < K_; k0 += 128) {
        if (tid < 128) kns[tid] = knorm[k0 + tid];
        float acc[8][8];
#pragma unroll
        for (int i = 0; i < 8; ++i)
#pragma unroll
            for (int j = 0; j < 8; ++j) acc[i][j] = 0.f;
        for (int cc = 0; cc < C_; cc += 16) {
            __syncthreads();
#pragma unroll
            for (int j = 0; j < 2; ++j) {
                int f = tid + 256 * j;
                int cl = f >> 5;
                int t4 = (f & 31) * 4;
                float4 v = *(const float4*)(xbase + (size_t)(cc + cl) * T_ + t4);
                *(float4*)&Xs[cl * 128 + t4] = v;
            }
#pragma unroll
            for (int j = 0; j < 2; ++j) {
                int f = tid + 256 * j;
                int kl = f >> 2;
                int c4 = (f & 3) * 4;
                float4 v = *(const float4*)(cb + (size_t)(k0 + kl) * C_ + cc + c4);
                Bs[(c4 + 0) * 132 + kl] = v.x;
                Bs[(c4 + 1) * 132 + kl] = v.y;
                Bs[(c4 + 2) * 132 + kl] = v.z;
                Bs[(c4 + 3) * 132 + kl] = v.w;
            }
            __syncthreads();
#pragma unroll
            for (int c = 0; c < 16; ++c) {
                float4 xa = *(const float4*)&Xs[c * 128 + ty * 8];
                float4 xb2 = *(const float4*)&Xs[c * 128 + ty * 8 + 4];
                float4 ba = *(const float4*)&Bs[c * 132 + tx * 8];
                float4 bb = *(const float4*)&Bs[c * 132 + tx * 8 + 4];
                float xr[8] = {xa.x, xa.y, xa.z, xa.w, xb2.x, xb2.y, xb2.z, xb2.w};
                float br[8] = {ba.x, ba.y, ba.z, ba.w, bb.x, bb.y, bb.z, bb.w};
#pragma unroll
                for (int i = 0; i < 8; ++i)
#pragma unroll
                    for (int j = 0; j < 8; ++j)
                        acc[i][j] = fmaf(xr[i], br[j], acc[i][j]);
            }
        }
#pragma unroll
        for (int j = 0; j < 8; ++j) {
            const int kk = k0 + tx * 8 + j;
            const float kn = kns[tx * 8 + j];
#pragma unroll
            for (int i = 0; i < 8; ++i) {
                float s = fmaf(-2.f, acc[i][j], kn);
                if (s < best[i]) { best[i] = s; bestk[i] = kk; }
            }
        }
        __syncthreads();
    }
#pragma unroll
    for (int i = 0; i < 8; ++i) {
        redv[(ty * 8 + i) * 16 + tx] = best[i];
        redk[(ty * 8 + i) * 16 + tx] = bestk[i];
    }
    __syncthreads();
    if (tid < 128) {
        float bv = redv[tid * 16];
        int bk = redk[tid * 16];
#pragma unroll
        for (int j = 1; j < 16; ++j) {
            float v = redv[tid * 16 + j];
            int kj = redk[tid * 16 + j];
            if (v < bv || (v == bv && kj < bk)) { bv = v; bk = kj; }
        }
        idxs[tid] = bk;
    }
    __syncthreads();
    const int tg = (tid & 31) * 4;
    const int cs = tid >> 5;
    const float* r0 = cb + (size_t)idxs[tg + 0] * C_;
    const float* r1 = cb + (size_t)idxs[tg + 1] * C_;
    const float* r2 = cb + (size_t)idxs[tg + 2] * C_;
    const float* r3 = cb + (size_t)idxs[tg + 3] * C_;
    float* obase = out + (size_t)n * C_ * T_ + t0 + tg;
    for (int c = cs; c < C_; c += 8) {
        float4 v;
        v.x = r0[c]; v.y = r1[c]; v.z = r2[c]; v.w = r3[c];
        *(float4*)&obase[(size_t)c * T_] = v;
    }
}

extern "C" void kernel_launch(void* const* d_in, const int* in_sizes, int n_in,
                              void* d_out, int out_size, void* d_ws, size_t ws_size,
                              hipStream_t stream) {
    const float* x = (const float*)d_in[0];    // [32,512,2048] fp32
    const float* cb = (const float*)d_in[1];   // [1024,512] fp32
    float* out = (float*)d_out;
    char* ws = (char*)d_ws;

    if (ws_size < WS_NEED) {
        float* kn = (float*)ws;
        int* cnt0 = (int*)(ws + 4096);
        knorm_init_kernel<<<K_, 64, 0, stream>>>(cb, kn, out, cnt0);
        vq_fallback_kernel<<<(NT_) / 128, 256, 0, stream>>>(x, cb, kn, out);
        return;
    }

    f16* cbws = (f16*)(ws + OFF_CBH);
    float* knorm = (float*)(ws + OFF_KN);
    int* cnt = (int*)(ws + OFF_CNT);
    int* list = (int*)(ws + OFF_LST);

    knorm_init_kernel<<<K_, 64, 0, stream>>>(cb, knorm, out, cnt);
    conv_cb_kernel<<<128, 256, 0, stream>>>(cb, cbws);
    vq_fused2_kernel<<<512, 256, 0, stream>>>(x, cb, cbws, knorm, out, cnt, list);
    rescan3b_kernel<<<512, 256, 0, stream>>>(x, cb, knorm, cnt, list, out);
}

// Round 9
// 517.199 us; speedup vs baseline: 1.2868x; 1.2868x over previous
//
#include <hip/hip_runtime.h>

#define N_ 32
#define C_ 512
#define T_ 2048
#define K_ 1024
#define NT_ 65536
#define EPS_ 0.12f

typedef _Float16 f16;
typedef f16 f16x2 __attribute__((ext_vector_type(2)));
typedef f16 f16x4 __attribute__((ext_vector_type(4)));
typedef f16 f16x8 __attribute__((ext_vector_type(8)));
typedef float f32x4 __attribute__((ext_vector_type(4)));

// ---- ws layout (bytes) ----
#define OFF_XH   ((size_t)0)                 // f16 x, tiled [512 tblk][16 co][128 t][32 c]
#define OFF_CBH  ((size_t)67108864)          // f16 cb, tiled [8 kblk][16 co][128 k][32 c]
#define OFF_KN   ((size_t)68157440)          // fp32 knorm [1024]
#define OFF_TOP  ((size_t)68161536)          // float4 top2 [512*8][128]
#define OFF_IDX  ((size_t)76550144)          // int idx [65536]
#define OFF_CNT  ((size_t)76812288)          // int count (zeroed by knorm_init)
#define OFF_LST  ((size_t)76812544)          // int worklist [65536]
#define WS_NEED  ((size_t)77074688)

#define GLOAD(g, l) __builtin_amdgcn_global_load_lds( \
    (__attribute__((address_space(1))) const unsigned int*)(const void*)(g), \
    (__attribute__((address_space(3))) unsigned int*)(void*)(l), 16, 0, 0)

// ---------------- Kernel 1: codebook norms + zero scalars + zero worklist count ----------------
__global__ void knorm_init_kernel(const float* __restrict__ cb,
                                  float* __restrict__ knorm,
                                  float* __restrict__ out,
                                  int* __restrict__ cnt) {
    const int k = blockIdx.x;
    const int lane = threadIdx.x;
    const float* row = cb + (size_t)k * C_;
    float s = 0.f;
#pragma unroll
    for (int j = 0; j < C_ / 64; ++j) {
        float v = row[lane + 64 * j];
        s += v * v;
    }
#pragma unroll
    for (int off = 32; off > 0; off >>= 1) s += __shfl_down(s, off, 64);
    if (lane == 0) knorm[k] = s;
    if (k == 0 && lane == 0) {
        out[(size_t)N_ * C_ * T_ + 0] = 0.f;
        out[(size_t)N_ * C_ * T_ + 1] = 0.f;
        *cnt = 0;
    }
}

// ---------------- Kernel 2: convert codebook to tiled f16 ----------------
__global__ void __launch_bounds__(256) conv_cb_kernel(const float* __restrict__ cb,
                                                      f16* __restrict__ cbws) {
    const int tid = threadIdx.x;
    const int kblk = blockIdx.x >> 4;
    const int co = blockIdx.x & 15;
    const float* src = cb + (size_t)kblk * 128 * C_ + co * 32;
    f16* dst = cbws + (size_t)kblk * 65536 + (size_t)co * 4096;
#pragma unroll
    for (int j = 0; j < 4; ++j) {
        int f = tid + 256 * j;            // 0..1023
        int k_l = f >> 3;                 // 0..127
        int c4 = (f & 7) * 4;             // 0..28
        float4 v = *(const float4*)(src + (size_t)k_l * C_ + c4);
        f16x4 h = {(f16)v.x, (f16)v.y, (f16)v.z, (f16)v.w};
        *(f16x4*)(dst + (size_t)k_l * 32 + c4) = h;
    }
}

// ---------------- Kernel 3: convert x to tiled f16 (R7-verified split version) ----------------
// One block per (t-tile, co): 8192 independent single-phase blocks -> TLP hides the
// load latency that the old 16-phase serial loop exposed.
__global__ void __launch_bounds__(256) conv_x_kernel(const float* __restrict__ x,
                                                     f16* __restrict__ xws) {
    __shared__ f16 trans[128 * 34];
    const int tid = threadIdx.x;
    const int bb = blockIdx.x;                // 0..8191
    const int b = bb >> 4, co = bb & 15;      // b: t-tile, co: 32-c slab
    const int n = b >> 4;
    const int t0 = (b & 15) << 7;
    const float* xb = x + (size_t)n * C_ * T_ + t0;
    f16* outb = xws + (size_t)b * 65536;
    const int cp = tid >> 5;
    const int s = tid & 31;
#pragma unroll
    for (int j = 0; j < 2; ++j) {
        int cpp = cp + 8 * j;
        int c0 = cpp * 2;
        float4 v0 = *(const float4*)(xb + (size_t)(co * 32 + c0) * T_ + s * 4);
        float4 v1 = *(const float4*)(xb + (size_t)(co * 32 + c0 + 1) * T_ + s * 4);
        f16x2 w0 = {(f16)v0.x, (f16)v1.x};
        f16x2 w1 = {(f16)v0.y, (f16)v1.y};
        f16x2 w2 = {(f16)v0.z, (f16)v1.z};
        f16x2 w3 = {(f16)v0.w, (f16)v1.w};
        *(f16x2*)&trans[(s * 4 + 0) * 34 + c0] = w0;
        *(f16x2*)&trans[(s * 4 + 1) * 34 + c0] = w1;
        *(f16x2*)&trans[(s * 4 + 2) * 34 + c0] = w2;
        *(f16x2*)&trans[(s * 4 + 3) * 34 + c0] = w3;
    }
    __syncthreads();
#pragma unroll
    for (int j = 0; j < 8; ++j) {
        int p = tid + 256 * j;
        int t_l = p >> 4;
        int cpo = p & 15;
        f16x2 v = *(const f16x2*)&trans[t_l * 34 + cpo * 2];
        *(f16x2*)(outb + (size_t)co * 4096 + t_l * 32 + cpo * 2) = v;
    }
}

// ---------------- Kernel 4: MFMA distance + per-row top2 (R4-verified, 134.7 us) ----------------
__global__ void __launch_bounds__(256) mfma_top2_kernel(const f16* __restrict__ xws,
                                                        const f16* __restrict__ cbws,
                                                        const float* __restrict__ knorm,
                                                        float4* __restrict__ topout) {
    __shared__ __align__(16) char smem[32768];   // buf0: As|Bs (16KB), buf1: As|Bs (16KB)
    __shared__ float kns[128];
    __shared__ float mrg[128 * 2 * 3];

    const int tid = threadIdx.x;
    const int lane = tid & 63, w = tid >> 6;
    const int wy = w >> 1, wx = w & 1;
    const int col = lane & 15, quad = lane >> 4;

    // XCD-chunked bijective swizzle: XCD (blockIdx.x & 7) owns bl in [512*xcd, 512*(xcd+1))
    const int bl = (blockIdx.x & 7) * 512 + (blockIdx.x >> 3);
    const int tblk = bl >> 3, kblk = bl & 7;

    // source-side chunk swizzle: lane l stages (row = l>>2, chunk = (l&3) ^ ((l>>3)&3))
    const int swz = ((lane >> 2) << 6) + (((lane & 3) ^ ((lane >> 3) & 3)) << 4);

    const char* gA = (const char*)xws + (size_t)tblk * 131072 + w * 2048 + swz;
    const char* gB = (const char*)cbws + (size_t)kblk * 131072 + w * 2048 + swz;
    char* lA = smem + w * 2048;          // A slice within buf0
    char* lB = smem + 8192 + w * 2048;   // B slice within buf0

    if (tid < 128) kns[tid] = knorm[kblk * 128 + tid];

    f32x4 acc[4][4];
#pragma unroll
    for (int i = 0; i < 4; ++i)
#pragma unroll
        for (int j = 0; j < 4; ++j) acc[i][j] = (f32x4){0.f, 0.f, 0.f, 0.f};

    // swizzled read: row-within-16 is col, so matching XOR is (col>>1)&3 on the chunk
    const int rchunk = (quad ^ ((col >> 1) & 3)) * 8;
    const int aoff[4] = {(wy * 64 + 0 * 16 + col) * 32 + rchunk,
                         (wy * 64 + 1 * 16 + col) * 32 + rchunk,
                         (wy * 64 + 2 * 16 + col) * 32 + rchunk,
                         (wy * 64 + 3 * 16 + col) * 32 + rchunk};
    const int boff[4] = {(wx * 64 + 0 * 16 + col) * 32 + rchunk,
                         (wx * 64 + 1 * 16 + col) * 32 + rchunk,
                         (wx * 64 + 2 * 16 + col) * 32 + rchunk,
                         (wx * 64 + 3 * 16 + col) * 32 + rchunk};

    // prologue: stage co=0 into buf0
    GLOAD(gA, lA);
    GLOAD(gA + 1024, lA + 1024);
    GLOAD(gB, lB);
    GLOAD(gB + 1024, lB + 1024);
    __syncthreads();

    int cur = 0;
    for (int co = 0; co < 16; ++co) {
        if (co < 15) {                         // prefetch next phase into other buffer
            const size_t go = (size_t)(co + 1) * 8192;
            const int nb = (cur ^ 1) * 16384;
            GLOAD(gA + go, lA + nb);
            GLOAD(gA + go + 1024, lA + nb + 1024);
            GLOAD(gB + go, lB + nb);
            GLOAD(gB + go + 1024, lB + nb + 1024);
        }
        const f16* As = (const f16*)(smem + cur * 16384);
        const f16* Bs = (const f16*)(smem + 8192 + cur * 16384);
        f16x8 af[4], bf[4];
#pragma unroll
        for (int ti = 0; ti < 4; ++ti) af[ti] = *(const f16x8*)(As + aoff[ti]);
#pragma unroll
        for (int ki = 0; ki < 4; ++ki) bf[ki] = *(const f16x8*)(Bs + boff[ki]);
#pragma unroll
        for (int ti = 0; ti < 4; ++ti)
#pragma unroll
            for (int ki = 0; ki < 4; ++ki)
                acc[ti][ki] = __builtin_amdgcn_mfma_f32_16x16x32_f16(af[ti], bf[ki], acc[ti][ki], 0, 0, 0);
        __syncthreads();                       // drains prefetch; protects buf reuse
        cur ^= 1;
    }

#pragma unroll
    for (int ti = 0; ti < 4; ++ti) {
#pragma unroll
        for (int reg = 0; reg < 4; ++reg) {
            float rv1 = 3.4e38f, rv2 = 3.4e38f;
            int ri1 = 0;
#pragma unroll
            for (int ki = 0; ki < 4; ++ki) {
                int kl = wx * 64 + ki * 16 + col;
                float sc = fmaf(-2.f, acc[ti][ki][reg], kns[kl]);
                int kg = kblk * 128 + kl;
                if (sc < rv1) { rv2 = rv1; rv1 = sc; ri1 = kg; }
                else if (sc < rv2) rv2 = sc;
            }
#pragma unroll
            for (int m = 1; m <= 8; m <<= 1) {
                float ov1 = __shfl_xor(rv1, m, 64);
                float ov2 = __shfl_xor(rv2, m, 64);
                int oi1 = __shfl_xor(ri1, m, 64);
                float nv2 = fminf(fminf(rv2, ov2), fmaxf(rv1, ov1));
                if (ov1 < rv1 || (ov1 == rv1 && oi1 < ri1)) { rv1 = ov1; ri1 = oi1; }
                rv2 = nv2;
            }
            if (col == 0) {
                int t_l = wy * 64 + ti * 16 + quad * 4 + reg;
                float* p = &mrg[(t_l * 2 + wx) * 3];
                p[0] = rv1; p[1] = __int_as_float(ri1); p[2] = rv2;
            }
        }
    }
    __syncthreads();
    if (tid < 128) {
        const float* pa = &mrg[tid * 6];
        const float* pb = &mrg[tid * 6 + 3];
        float v1 = pa[0], v2 = pa[2];
        int i1 = __float_as_int(pa[1]);
        float ov1 = pb[0], ov2 = pb[2];
        int oi1 = __float_as_int(pb[1]);
        float nv2 = fminf(fminf(v2, ov2), fmaxf(v1, ov1));
        if (ov1 < v1 || (ov1 == v1 && oi1 < i1)) { v1 = ov1; i1 = oi1; }
        float4 o;
        o.x = v1; o.y = __int_as_float(i1); o.z = nv2; o.w = 0.f;
        topout[(size_t)bl * 128 + tid] = o;
    }
}

// ---------------- Kernel 5: combine partials -> idx, append marginal rows to worklist ----------------
__global__ void __launch_bounds__(256) combine_kernel(const float4* __restrict__ top,
                                                      int* __restrict__ idx,
                                                      int* __restrict__ cnt,
                                                      int* __restrict__ list) {
    const int r = blockIdx.x * 256 + threadIdx.x;  // 0..65535
    const int tblk = r >> 7, tin = r & 127;
    float v1 = 3.4e38f, v2 = 3.4e38f;
    int i1 = 0;
#pragma unroll
    for (int kb = 0; kb < 8; ++kb) {
        float4 e = top[((size_t)(tblk * 8 + kb)) * 128 + tin];
        float ev1 = e.x, ev2 = e.z;
        int ei1 = __float_as_int(e.y);
        float nv2 = fminf(fminf(v2, ev2), fmaxf(v1, ev1));
        if (ev1 < v1 || (ev1 == v1 && ei1 < i1)) { v1 = ev1; i1 = ei1; }
        v2 = nv2;
    }
    idx[r] = i1;
    if (v2 <= v1 + 2.f * EPS_) {
        int p = atomicAdd(cnt, 1);
        list[p] = r;
    }
}

// ---------------- Kernel 6: exact fp32 rescan (R1-verified, 2048 blocks, idx write) ----------------
__global__ void __launch_bounds__(256) rescan3_kernel(const float* __restrict__ x,
                                                      const float* __restrict__ cb,
                                                      const float* __restrict__ knorm,
                                                      const int* __restrict__ cnt,
                                                      const int* __restrict__ list,
                                                      int* __restrict__ idx) {
    __shared__ __align__(16) f32x4 tile[4][512];   // 32KB: [c4][code ^ (c4<<1)]
    __shared__ __align__(16) float xs[4][512];     // 8KB
    __shared__ float redv[4][256];                 // 4KB
    __shared__ int redk[4][256];                   // 4KB
    const int tid = threadIdx.x;
    const int nf = *cnt;
    for (int base = blockIdx.x * 4; base < nf; base += gridDim.x * 4) {
        const int nr = (nf - base < 4) ? (nf - base) : 4;
        __syncthreads();   // protect xs/tile reuse across grid-stride iterations
        for (int i = tid; i < nr * 512; i += 256) {
            int r = i >> 9, c = i & 511;
            int rr = list[base + r];
            int n = rr >> 11, t = rr & 2047;
            xs[r][c] = x[(size_t)n * C_ * T_ + (size_t)c * T_ + t];
        }

        float bv[4];
        int bk[4];
#pragma unroll
        for (int r = 0; r < 4; ++r) { bv[r] = 3.4e38f; bk[r] = 0; }

        for (int kpass = 0; kpass < 2; ++kpass) {
            float acc[2][4];   // [j(code)][item]
#pragma unroll
            for (int j = 0; j < 2; ++j)
#pragma unroll
                for (int r = 0; r < 4; ++r) acc[j][r] = 0.f;

            for (int cc = 0; cc < 32; ++cc) {      // 16-float c-chunks
                __syncthreads();
#pragma unroll
                for (int jj = 0; jj < 8; ++jj) {
                    int q = tid + 256 * jj;        // 0..2047
                    int row = q >> 2;              // 0..511
                    int c4 = q & 3;                // 0..3
                    f32x4 v = *(const f32x4*)(cb + (size_t)(kpass * 512 + row) * C_ + cc * 16 + c4 * 4);
                    tile[c4][row ^ (c4 << 1)] = v;
                }
                __syncthreads();
                f32x4 xv[4][4];
#pragma unroll
                for (int r = 0; r < 4; ++r)
#pragma unroll
                    for (int c4 = 0; c4 < 4; ++c4)
                        xv[r][c4] = *(const f32x4*)&xs[r][cc * 16 + c4 * 4];
#pragma unroll
                for (int j = 0; j < 2; ++j) {
                    int kl = tid + 256 * j;
#pragma unroll
                    for (int c4 = 0; c4 < 4; ++c4) {
                        f32x4 cv = tile[c4][kl ^ (c4 << 1)];
#pragma unroll
                        for (int r = 0; r < 4; ++r) {
                            acc[j][r] = fmaf(cv.x, xv[r][c4].x, acc[j][r]);
                            acc[j][r] = fmaf(cv.y, xv[r][c4].y, acc[j][r]);
                            acc[j][r] = fmaf(cv.z, xv[r][c4].z, acc[j][r]);
                            acc[j][r] = fmaf(cv.w, xv[r][c4].w, acc[j][r]);
                        }
                    }
                }
            }
#pragma unroll
            for (int j = 0; j < 2; ++j) {
                int k = kpass * 512 + tid + 256 * j;
                float kn = knorm[k];
#pragma unroll
                for (int r = 0; r < 4; ++r) {
                    float sc = fmaf(-2.f, acc[j][r], kn);
                    if (sc < bv[r]) { bv[r] = sc; bk[r] = k; }
                }
            }
        }
#pragma unroll
        for (int r = 0; r < 4; ++r) {
            redv[r][tid] = bv[r];
            redk[r][tid] = bk[r];
        }
        __syncthreads();
        for (int off = 128; off > 0; off >>= 1) {
            if (tid < off) {
#pragma unroll
                for (int r = 0; r < 4; ++r) {
                    float ov = redv[r][tid + off];
                    int ok = redk[r][tid + off];
                    if (ov < redv[r][tid] || (ov == redv[r][tid] && ok < redk[r][tid])) {
                        redv[r][tid] = ov;
                        redk[r][tid] = ok;
                    }
                }
            }
            __syncthreads();
        }
        if (tid == 0) {
            for (int r = 0; r < nr; ++r) idx[list[base + r]] = redk[r][0];
        }
    }
}

// ---------------- Kernel 7: gather codebook rows to output ----------------
__global__ void __launch_bounds__(256) gather_kernel(const float* __restrict__ cb,
                                                     const int* __restrict__ idx,
                                                     float* __restrict__ out) {
    __shared__ int idxs[128];
    const int tid = threadIdx.x;
    const int b = blockIdx.x;
    const int n = b >> 4;
    const int t0 = (b & 15) << 7;
    if (tid < 128) idxs[tid] = idx[b * 128 + tid];
    __syncthreads();
    const int tg = (tid & 31) * 4;
    const int cs = tid >> 5;
    const float* r0 = cb + (size_t)idxs[tg + 0] * C_;
    const float* r1 = cb + (size_t)idxs[tg + 1] * C_;
    const float* r2 = cb + (size_t)idxs[tg + 2] * C_;
    const float* r3 = cb + (size_t)idxs[tg + 3] * C_;
    float* obase = out + (size_t)n * C_ * T_ + t0 + tg;
    for (int c = cs; c < C_; c += 8) {
        float4 v;
        v.x = r0[c]; v.y = r1[c]; v.z = r2[c]; v.w = r3[c];
        *(float4*)&obase[(size_t)c * T_] = v;
    }
}

// ---------------- Fallback (round-1 fp32 path, verified correct) ----------------
__global__ void __launch_bounds__(256)
vq_fallback_kernel(const float* __restrict__ x, const float* __restrict__ cb,
                   const float* __restrict__ knorm, float* __restrict__ out) {
    __shared__ float smem[4416];
    float* Xs = smem;
    float* Bs = smem + 2048;
    float* kns = smem + 4160;
    int* idxs = (int*)(smem + 4288);
    float* redv = smem;
    int* redk = (int*)(smem + 2048);

    const int tid = threadIdx.x;
    const int tx = tid & 15;
    const int ty = tid >> 4;
    const int b = blockIdx.x;
    const int n = b >> 4;
    const int t0 = (b & 15) * 128;
    const float* xbase = x + (size_t)n * C_ * T_ + t0;

    float best[8];
    int bestk[8];
#pragma unroll
    for (int i = 0; i < 8; ++i) { best[i] = 3.4e38f; bestk[i] = 0; }

    for (int k0 = 0; k0 < K_; k0 += 128) {
        if (tid < 128) kns[tid] = knorm[k0 + tid];
        float acc[8][8];
#pragma unroll
        for (int i = 0; i < 8; ++i)
#pragma unroll
            for (int j = 0; j < 8; ++j) acc[i][j] = 0.f;
        for (int cc = 0; cc < C_; cc += 16) {
            __syncthreads();
#pragma unroll
            for (int j = 0; j < 2; ++j) {
                int f = tid + 256 * j;
                int cl = f >> 5;
                int t4 = (f & 31) * 4;
                float4 v = *(const float4*)(xbase + (size_t)(cc + cl) * T_ + t4);
                *(float4*)&Xs[cl * 128 + t4] = v;
            }
#pragma unroll
            for (int j = 0; j < 2; ++j) {
                int f = tid + 256 * j;
                int kl = f >> 2;
                int c4 = (f & 3) * 4;
                float4 v = *(const float4*)(cb + (size_t)(k0 + kl) * C_ + cc + c4);
                Bs[(c4 + 0) * 132 + kl] = v.x;
                Bs[(c4 + 1) * 132 + kl] = v.y;
                Bs[(c4 + 2) * 132 + kl] = v.z;
                Bs[(c4 + 3) * 132 + kl] = v.w;
            }
            __syncthreads();
#pragma unroll
            for (int c = 0; c < 16; ++c) {
                float4 xa = *(const float4*)&Xs[c * 128 + ty * 8];
                float4 xb2 = *(const float4*)&Xs[c * 128 + ty * 8 + 4];
                float4 ba = *(const float4*)&Bs[c * 132 + tx * 8];
                float4 bb = *(const float4*)&Bs[c * 132 + tx * 8 + 4];
                float xr[8] = {xa.x, xa.y, xa.z, xa.w, xb2.x, xb2.y, xb2.z, xb2.w};
                float br[8] = {ba.x, ba.y, ba.z, ba.w, bb.x, bb.y, bb.z, bb.w};
#pragma unroll
                for (int i = 0; i < 8; ++i)
#pragma unroll
                    for (int j = 0; j < 8; ++j)
                        acc[i][j] = fmaf(xr[i], br[j], acc[i][j]);
            }
        }
#pragma unroll
        for (int j = 0; j < 8; ++j) {
            const int kk = k0 + tx * 8 + j;
            const float kn = kns[tx * 8 + j];
#pragma unroll
            for (int i = 0; i < 8; ++i) {
                float s = fmaf(-2.f, acc[i][j], kn);
                if (s < best[i]) { best[i] = s; bestk[i] = kk; }
            }
        }
        __syncthreads();
    }
#pragma unroll
    for (int i = 0; i < 8; ++i) {
        redv[(ty * 8 + i) * 16 + tx] = best[i];
        redk[(ty * 8 + i) * 16 + tx] = bestk[i];
    }
    __syncthreads();
    if (tid < 128) {
        float bv = redv[tid * 16];
        int bk = redk[tid * 16];
#pragma unroll
        for (int j = 1; j < 16; ++j) {
            float v = redv[tid * 16 + j];
            int kj = redk[tid * 16 + j];
            if (v < bv || (v == bv && kj < bk)) { bv = v; bk = kj; }
        }
        idxs[tid] = bk;
    }
    __syncthreads();
    const int tg = (tid & 31) * 4;
    const int cs = tid >> 5;
    const float* r0 = cb + (size_t)idxs[tg + 0] * C_;
    const float* r1 = cb + (size_t)idxs[tg + 1] * C_;
    const float* r2 = cb + (size_t)idxs[tg + 2] * C_;
    const float* r3 = cb + (size_t)idxs[tg + 3] * C_;
    float* obase = out + (size_t)n * C_ * T_ + t0 + tg;
    for (int c = cs; c < C_; c += 8) {
        float4 v;
        v.x = r0[c]; v.y = r1[c]; v.z = r2[c]; v.w = r3[c];
        *(float4*)&obase[(size_t)c * T_] = v;
    }
}

extern "C" void kernel_launch(void* const* d_in, const int* in_sizes, int n_in,
                              void* d_out, int out_size, void* d_ws, size_t ws_size,
                              hipStream_t stream) {
    const float* x = (const float*)d_in[0];    // [32,512,2048] fp32
    const float* cb = (const float*)d_in[1];   // [1024,512] fp32
    float* out = (float*)d_out;
    char* ws = (char*)d_ws;

    if (ws_size < WS_NEED) {
        float* kn = (float*)ws;
        int* cnt0 = (int*)(ws + 4096);
        knorm_init_kernel<<<K_, 64, 0, stream>>>(cb, kn, out, cnt0);
        vq_fallback_kernel<<<(NT_) / 128, 256, 0, stream>>>(x, cb, kn, out);
        return;
    }

    f16* xws = (f16*)(ws + OFF_XH);
    f16* cbws = (f16*)(ws + OFF_CBH);
    float* knorm = (float*)(ws + OFF_KN);
    float4* top = (float4*)(ws + OFF_TOP);
    int* idx = (int*)(ws + OFF_IDX);
    int* cnt = (int*)(ws + OFF_CNT);
    int* list = (int*)(ws + OFF_LST);

    knorm_init_kernel<<<K_, 64, 0, stream>>>(cb, knorm, out, cnt);
    conv_cb_kernel<<<128, 256, 0, stream>>>(cb, cbws);
    conv_x_kernel<<<8192, 256, 0, stream>>>(x, xws);
    mfma_top2_kernel<<<4096, 256, 0, stream>>>(xws, cbws, knorm, top);
    combine_kernel<<<256, 256, 0, stream>>>(top, idx, cnt, list);
    rescan3_kernel<<<2048, 256, 0, stream>>>(x, cb, knorm, cnt, list, idx);
    gather_kernel<<<512, 256, 0, stream>>>(cb, idx, out);
}

// Round 11
// 472.415 us; speedup vs baseline: 1.4088x; 1.0948x over previous
//
#include <hip/hip_runtime.h>

#define N_ 32
#define C_ 512
#define T_ 2048
#define K_ 1024
#define NT_ 65536
#define EPS_ 0.12f

typedef _Float16 f16;
typedef f16 f16x2 __attribute__((ext_vector_type(2)));
typedef f16 f16x4 __attribute__((ext_vector_type(4)));
typedef f16 f16x8 __attribute__((ext_vector_type(8)));
typedef float f32x4 __attribute__((ext_vector_type(4)));

// ---- ws layout (bytes) ----
#define OFF_XH   ((size_t)0)                 // f16 x, tiled [512 tblk][16 co][128 t][32 c]
#define OFF_CBH  ((size_t)67108864)          // f16 cb, tiled [8 kblk][16 co][128 k][32 c]
#define OFF_KN   ((size_t)68157440)          // fp32 knorm [1024]
#define OFF_TOP  ((size_t)68161536)          // float4 top2 [512*8][128]
#define OFF_IDX  ((size_t)76550144)          // int idx [65536]
#define OFF_CNT  ((size_t)76812288)          // int count (zeroed by knorm_init)
#define OFF_LST  ((size_t)76812544)          // int worklist [65536]
#define WS_NEED  ((size_t)77074688)

#define GLOAD(g, l) __builtin_amdgcn_global_load_lds( \
    (__attribute__((address_space(1))) const unsigned int*)(const void*)(g), \
    (__attribute__((address_space(3))) unsigned int*)(void*)(l), 16, 0, 0)

// ---------------- Kernel 1: codebook norms + zero scalars + zero worklist count ----------------
__global__ void knorm_init_kernel(const float* __restrict__ cb,
                                  float* __restrict__ knorm,
                                  float* __restrict__ out,
                                  int* __restrict__ cnt) {
    const int k = blockIdx.x;
    const int lane = threadIdx.x;
    const float* row = cb + (size_t)k * C_;
    float s = 0.f;
#pragma unroll
    for (int j = 0; j < C_ / 64; ++j) {
        float v = row[lane + 64 * j];
        s += v * v;
    }
#pragma unroll
    for (int off = 32; off > 0; off >>= 1) s += __shfl_down(s, off, 64);
    if (lane == 0) knorm[k] = s;
    if (k == 0 && lane == 0) {
        out[(size_t)N_ * C_ * T_ + 0] = 0.f;
        out[(size_t)N_ * C_ * T_ + 1] = 0.f;
        *cnt = 0;
    }
}

// ---------------- Kernel 2: convert codebook to tiled f16 ----------------
__global__ void __launch_bounds__(256) conv_cb_kernel(const float* __restrict__ cb,
                                                      f16* __restrict__ cbws) {
    const int tid = threadIdx.x;
    const int kblk = blockIdx.x >> 4;
    const int co = blockIdx.x & 15;
    const float* src = cb + (size_t)kblk * 128 * C_ + co * 32;
    f16* dst = cbws + (size_t)kblk * 65536 + (size_t)co * 4096;
#pragma unroll
    for (int j = 0; j < 4; ++j) {
        int f = tid + 256 * j;            // 0..1023
        int k_l = f >> 3;                 // 0..127
        int c4 = (f & 7) * 4;             // 0..28
        float4 v = *(const float4*)(src + (size_t)k_l * C_ + c4);
        f16x4 h = {(f16)v.x, (f16)v.y, (f16)v.z, (f16)v.w};
        *(f16x4*)(dst + (size_t)k_l * 32 + c4) = h;
    }
}

// ---------------- Kernel 3: convert x to tiled f16 (R7/R9-verified split version) ----------------
__global__ void __launch_bounds__(256) conv_x_kernel(const float* __restrict__ x,
                                                     f16* __restrict__ xws) {
    __shared__ f16 trans[128 * 34];
    const int tid = threadIdx.x;
    const int bb = blockIdx.x;                // 0..8191
    const int b = bb >> 4, co = bb & 15;      // b: t-tile, co: 32-c slab
    const int n = b >> 4;
    const int t0 = (b & 15) << 7;
    const float* xb = x + (size_t)n * C_ * T_ + t0;
    f16* outb = xws + (size_t)b * 65536;
    const int cp = tid >> 5;
    const int s = tid & 31;
#pragma unroll
    for (int j = 0; j < 2; ++j) {
        int cpp = cp + 8 * j;
        int c0 = cpp * 2;
        float4 v0 = *(const float4*)(xb + (size_t)(co * 32 + c0) * T_ + s * 4);
        float4 v1 = *(const float4*)(xb + (size_t)(co * 32 + c0 + 1) * T_ + s * 4);
        f16x2 w0 = {(f16)v0.x, (f16)v1.x};
        f16x2 w1 = {(f16)v0.y, (f16)v1.y};
        f16x2 w2 = {(f16)v0.z, (f16)v1.z};
        f16x2 w3 = {(f16)v0.w, (f16)v1.w};
        *(f16x2*)&trans[(s * 4 + 0) * 34 + c0] = w0;
        *(f16x2*)&trans[(s * 4 + 1) * 34 + c0] = w1;
        *(f16x2*)&trans[(s * 4 + 2) * 34 + c0] = w2;
        *(f16x2*)&trans[(s * 4 + 3) * 34 + c0] = w3;
    }
    __syncthreads();
#pragma unroll
    for (int j = 0; j < 8; ++j) {
        int p = tid + 256 * j;
        int t_l = p >> 4;
        int cpo = p & 15;
        f16x2 v = *(const f16x2*)&trans[t_l * 34 + cpo * 2];
        *(f16x2*)(outb + (size_t)co * 4096 + t_l * 32 + cpo * 2) = v;
    }
}

// ---------------- Kernel 4: MFMA distance + per-row top2 (R4/R9-verified, 135.7 us) ----------------
__global__ void __launch_bounds__(256) mfma_top2_kernel(const f16* __restrict__ xws,
                                                        const f16* __restrict__ cbws,
                                                        const float* __restrict__ knorm,
                                                        float4* __restrict__ topout) {
    __shared__ __align__(16) char smem[32768];   // buf0: As|Bs (16KB), buf1: As|Bs (16KB)
    __shared__ float kns[128];
    __shared__ float mrg[128 * 2 * 3];

    const int tid = threadIdx.x;
    const int lane = tid & 63, w = tid >> 6;
    const int wy = w >> 1, wx = w & 1;
    const int col = lane & 15, quad = lane >> 4;

    // XCD-chunked bijective swizzle: XCD (blockIdx.x & 7) owns bl in [512*xcd, 512*(xcd+1))
    const int bl = (blockIdx.x & 7) * 512 + (blockIdx.x >> 3);
    const int tblk = bl >> 3, kblk = bl & 7;

    // source-side chunk swizzle: lane l stages (row = l>>2, chunk = (l&3) ^ ((l>>3)&3))
    const int swz = ((lane >> 2) << 6) + (((lane & 3) ^ ((lane >> 3) & 3)) << 4);

    const char* gA = (const char*)xws + (size_t)tblk * 131072 + w * 2048 + swz;
    const char* gB = (const char*)cbws + (size_t)kblk * 131072 + w * 2048 + swz;
    char* lA = smem + w * 2048;          // A slice within buf0
    char* lB = smem + 8192 + w * 2048;   // B slice within buf0

    if (tid < 128) kns[tid] = knorm[kblk * 128 + tid];

    f32x4 acc[4][4];
#pragma unroll
    for (int i = 0; i < 4; ++i)
#pragma unroll
        for (int j = 0; j < 4; ++j) acc[i][j] = (f32x4){0.f, 0.f, 0.f, 0.f};

    // swizzled read: row-within-16 is col, so matching XOR is (col>>1)&3 on the chunk
    const int rchunk = (quad ^ ((col >> 1) & 3)) * 8;
    const int aoff[4] = {(wy * 64 + 0 * 16 + col) * 32 + rchunk,
                         (wy * 64 + 1 * 16 + col) * 32 + rchunk,
                         (wy * 64 + 2 * 16 + col) * 32 + rchunk,
                         (wy * 64 + 3 * 16 + col) * 32 + rchunk};
    const int boff[4] = {(wx * 64 + 0 * 16 + col) * 32 + rchunk,
                         (wx * 64 + 1 * 16 + col) * 32 + rchunk,
                         (wx * 64 + 2 * 16 + col) * 32 + rchunk,
                         (wx * 64 + 3 * 16 + col) * 32 + rchunk};

    // prologue: stage co=0 into buf0
    GLOAD(gA, lA);
    GLOAD(gA + 1024, lA + 1024);
    GLOAD(gB, lB);
    GLOAD(gB + 1024, lB + 1024);
    __syncthreads();

    int cur = 0;
    for (int co = 0; co < 16; ++co) {
        if (co < 15) {                         // prefetch next phase into other buffer
            const size_t go = (size_t)(co + 1) * 8192;
            const int nb = (cur ^ 1) * 16384;
            GLOAD(gA + go, lA + nb);
            GLOAD(gA + go + 1024, lA + nb + 1024);
            GLOAD(gB + go, lB + nb);
            GLOAD(gB + go + 1024, lB + nb + 1024);
        }
        const f16* As = (const f16*)(smem + cur * 16384);
        const f16* Bs = (const f16*)(smem + 8192 + cur * 16384);
        f16x8 af[4], bf[4];
#pragma unroll
        for (int ti = 0; ti < 4; ++ti) af[ti] = *(const f16x8*)(As + aoff[ti]);
#pragma unroll
        for (int ki = 0; ki < 4; ++ki) bf[ki] = *(const f16x8*)(Bs + boff[ki]);
#pragma unroll
        for (int ti = 0; ti < 4; ++ti)
#pragma unroll
            for (int ki = 0; ki < 4; ++ki)
                acc[ti][ki] = __builtin_amdgcn_mfma_f32_16x16x32_f16(af[ti], bf[ki], acc[ti][ki], 0, 0, 0);
        __syncthreads();                       // drains prefetch; protects buf reuse
        cur ^= 1;
    }

#pragma unroll
    for (int ti = 0; ti < 4; ++ti) {
#pragma unroll
        for (int reg = 0; reg < 4; ++reg) {
            float rv1 = 3.4e38f, rv2 = 3.4e38f;
            int ri1 = 0;
#pragma unroll
            for (int ki = 0; ki < 4; ++ki) {
                int kl = wx * 64 + ki * 16 + col;
                float sc = fmaf(-2.f, acc[ti][ki][reg], kns[kl]);
                int kg = kblk * 128 + kl;
                if (sc < rv1) { rv2 = rv1; rv1 = sc; ri1 = kg; }
                else if (sc < rv2) rv2 = sc;
            }
#pragma unroll
            for (int m = 1; m <= 8; m <<= 1) {
                float ov1 = __shfl_xor(rv1, m, 64);
                float ov2 = __shfl_xor(rv2, m, 64);
                int oi1 = __shfl_xor(ri1, m, 64);
                float nv2 = fminf(fminf(rv2, ov2), fmaxf(rv1, ov1));
                if (ov1 < rv1 || (ov1 == rv1 && oi1 < ri1)) { rv1 = ov1; ri1 = oi1; }
                rv2 = nv2;
            }
            if (col == 0) {
                int t_l = wy * 64 + ti * 16 + quad * 4 + reg;
                float* p = &mrg[(t_l * 2 + wx) * 3];
                p[0] = rv1; p[1] = __int_as_float(ri1); p[2] = rv2;
            }
        }
    }
    __syncthreads();
    if (tid < 128) {
        const float* pa = &mrg[tid * 6];
        const float* pb = &mrg[tid * 6 + 3];
        float v1 = pa[0], v2 = pa[2];
        int i1 = __float_as_int(pa[1]);
        float ov1 = pb[0], ov2 = pb[2];
        int oi1 = __float_as_int(pb[1]);
        float nv2 = fminf(fminf(v2, ov2), fmaxf(v1, ov1));
        if (ov1 < v1 || (ov1 == v1 && oi1 < i1)) { v1 = ov1; i1 = oi1; }
        float4 o;
        o.x = v1; o.y = __int_as_float(i1); o.z = nv2; o.w = 0.f;
        topout[(size_t)bl * 128 + tid] = o;
    }
}

// ---------------- Kernel 5: combine partials -> idx, append marginal rows to worklist ----------------
__global__ void __launch_bounds__(256) combine_kernel(const float4* __restrict__ top,
                                                      int* __restrict__ idx,
                                                      int* __restrict__ cnt,
                                                      int* __restrict__ list) {
    const int r = blockIdx.x * 256 + threadIdx.x;  // 0..65535
    const int tblk = r >> 7, tin = r & 127;
    float v1 = 3.4e38f, v2 = 3.4e38f;
    int i1 = 0;
#pragma unroll
    for (int kb = 0; kb < 8; ++kb) {
        float4 e = top[((size_t)(tblk * 8 + kb)) * 128 + tin];
        float ev1 = e.x, ev2 = e.z;
        int ei1 = __float_as_int(e.y);
        float nv2 = fminf(fminf(v2, ev2), fmaxf(v1, ev1));
        if (ev1 < v1 || (ev1 == v1 && ei1 < i1)) { v1 = ev1; i1 = ei1; }
        v2 = nv2;
    }
    idx[r] = i1;
    if (v2 <= v1 + 2.f * EPS_) {
        int p = atomicAdd(cnt, 1);
        list[p] = r;
    }
}

// ---------------- Kernel 6: exact fp32 rescan (R1/R9-verified, 2048 blocks, idx write) ----------------
__global__ void __launch_bounds__(256) rescan3_kernel(const float* __restrict__ x,
                                                      const float* __restrict__ cb,
                                                      const float* __restrict__ knorm,
                                                      const int* __restrict__ cnt,
                                                      const int* __restrict__ list,
                                                      int* __restrict__ idx) {
    __shared__ __align__(16) f32x4 tile[4][512];   // 32KB: [c4][code ^ (c4<<1)]
    __shared__ __align__(16) float xs[4][512];     // 8KB
    __shared__ float redv[4][256];                 // 4KB
    __shared__ int redk[4][256];                   // 4KB
    const int tid = threadIdx.x;
    const int nf = *cnt;
    for (int base = blockIdx.x * 4; base < nf; base += gridDim.x * 4) {
        const int nr = (nf - base < 4) ? (nf - base) : 4;
        __syncthreads();   // protect xs/tile reuse across grid-stride iterations
        for (int i = tid; i < nr * 512; i += 256) {
            int r = i >> 9, c = i & 511;
            int rr = list[base + r];
            int n = rr >> 11, t = rr & 2047;
            xs[r][c] = x[(size_t)n * C_ * T_ + (size_t)c * T_ + t];
        }

        float bv[4];
        int bk[4];
#pragma unroll
        for (int r = 0; r < 4; ++r) { bv[r] = 3.4e38f; bk[r] = 0; }

        for (int kpass = 0; kpass < 2; ++kpass) {
            float acc[2][4];   // [j(code)][item]
#pragma unroll
            for (int j = 0; j < 2; ++j)
#pragma unroll
                for (int r = 0; r < 4; ++r) acc[j][r] = 0.f;

            for (int cc = 0; cc < 32; ++cc) {      // 16-float c-chunks
                __syncthreads();
#pragma unroll
                for (int jj = 0; jj < 8; ++jj) {
                    int q = tid + 256 * jj;        // 0..2047
                    int row = q >> 2;              // 0..511
                    int c4 = q & 3;                // 0..3
                    f32x4 v = *(const f32x4*)(cb + (size_t)(kpass * 512 + row) * C_ + cc * 16 + c4 * 4);
                    tile[c4][row ^ (c4 << 1)] = v;
                }
                __syncthreads();
                f32x4 xv[4][4];
#pragma unroll
                for (int r = 0; r < 4; ++r)
#pragma unroll
                    for (int c4 = 0; c4 < 4; ++c4)
                        xv[r][c4] = *(const f32x4*)&xs[r][cc * 16 + c4 * 4];
#pragma unroll
                for (int j = 0; j < 2; ++j) {
                    int kl = tid + 256 * j;
#pragma unroll
                    for (int c4 = 0; c4 < 4; ++c4) {
                        f32x4 cv = tile[c4][kl ^ (c4 << 1)];
#pragma unroll
                        for (int r = 0; r < 4; ++r) {
                            acc[j][r] = fmaf(cv.x, xv[r][c4].x, acc[j][r]);
                            acc[j][r] = fmaf(cv.y, xv[r][c4].y, acc[j][r]);
                            acc[j][r] = fmaf(cv.z, xv[r][c4].z, acc[j][r]);
                            acc[j][r] = fmaf(cv.w, xv[r][c4].w, acc[j][r]);
                        }
                    }
                }
            }
#pragma unroll
            for (int j = 0; j < 2; ++j) {
                int k = kpass * 512 + tid + 256 * j;
                float kn = knorm[k];
#pragma unroll
                for (int r = 0; r < 4; ++r) {
                    float sc = fmaf(-2.f, acc[j][r], kn);
                    if (sc < bv[r]) { bv[r] = sc; bk[r] = k; }
                }
            }
        }
#pragma unroll
        for (int r = 0; r < 4; ++r) {
            redv[r][tid] = bv[r];
            redk[r][tid] = bk[r];
        }
        __syncthreads();
        for (int off = 128; off > 0; off >>= 1) {
            if (tid < off) {
#pragma unroll
                for (int r = 0; r < 4; ++r) {
                    float ov = redv[r][tid + off];
                    int ok = redk[r][tid + off];
                    if (ov < redv[r][tid] || (ov == redv[r][tid] && ok < redk[r][tid])) {
                        redv[r][tid] = ov;
                        redk[r][tid] = ok;
                    }
                }
            }
            __syncthreads();
        }
        if (tid == 0) {
            for (int r = 0; r < nr; ++r) idx[list[base + r]] = redk[r][0];
        }
    }
}

// ---------------- Kernel 7: gather via transpose-through-LDS ----------------
// Old gather: per-thread scalar 4B reads from 4 scattered cb rows -> each wave load
// touches 64 cache lines (latency-bound). New: stage 32 code-rows into a 64KB LDS
// tile with coalesced 128B reads (8 lanes x f32x4 per row), XOR-swizzled t-slot
// (thi ^ (c&7), applied identically on store and load -> b128 bank floor on readout),
// then write out as f32x4, 128B contiguous per 8-lane group. Semantics identical:
// out[n][c][t0+t] = cb[idx[...]][c].
__global__ void __launch_bounds__(256) gather2_kernel(const float* __restrict__ cb,
                                                      const int* __restrict__ idx,
                                                      float* __restrict__ out) {
    __shared__ __align__(16) float tile[512 * 32];   // 64KB: [c][t-slot swizzled]
    __shared__ int idxs[128];
    const int tid = threadIdx.x;
    const int b = blockIdx.x;
    const int n = b >> 4;
    const int t0 = (b & 15) << 7;
    if (tid < 128) idxs[tid] = idx[b * 128 + tid];
    const int r = tid >> 3;        // 0..31: staged row / write c-row
    const int lane8 = tid & 7;     // staging c-segment
    const int tq = tid & 7;        // write t-quad

    for (int g = 0; g < 4; ++g) {
        __syncthreads();           // idxs ready (g=0); tile free (g>0)
        const float* src = cb + (size_t)idxs[g * 32 + r] * C_;
#pragma unroll
        for (int it = 0; it < 16; ++it) {
            int c4 = lane8 * 4 + it * 32;
            f32x4 v = *(const f32x4*)(src + c4);
#pragma unroll
            for (int i = 0; i < 4; ++i) {
                int c = c4 + i;
                tile[c * 32 + (((r >> 2) ^ (c & 7)) << 2) + (r & 3)] = v[i];
            }
        }
        __syncthreads();
        float* obase = out + (size_t)n * C_ * T_ + t0 + g * 32;
#pragma unroll
        for (int it = 0; it < 16; ++it) {
            int c = r + it * 32;   // r doubles as the write c-row (0..31)
            f32x4 wv = *(const f32x4*)&tile[c * 32 + ((tq ^ (c & 7)) << 2)];
            *(f32x4*)(obase + (size_t)c * T_ + tq * 4) = wv;
        }
    }
}

// ---------------- Fallback (round-1 fp32 path, verified correct) ----------------
__global__ void __launch_bounds__(256)
vq_fallback_kernel(const float* __restrict__ x, const float* __restrict__ cb,
                   const float* __restrict__ knorm, float* __restrict__ out) {
    __shared__ float smem[4416];
    float* Xs = smem;
    float* Bs = smem + 2048;
    float* kns = smem + 4160;
    int* idxs = (int*)(smem + 4288);
    float* redv = smem;
    int* redk = (int*)(smem + 2048);

    const int tid = threadIdx.x;
    const int tx = tid & 15;
    const int ty = tid >> 4;
    const int b = blockIdx.x;
    const int n = b >> 4;
    const int t0 = (b & 15) * 128;
    const float* xbase = x + (size_t)n * C_ * T_ + t0;

    float best[8];
    int bestk[8];
#pragma unroll
    for (int i = 0; i < 8; ++i) { best[i] = 3.4e38f; bestk[i] = 0; }

    for (int k0 = 0; k0 < K_; k0 += 128) {
        if (tid < 128) kns[tid] = knorm[k0 + tid];
        float acc[8][8];
#pragma unroll
        for (int i = 0; i < 8; ++i)
#pragma unroll
            for (int j = 0; j < 8; ++j) acc[i][j] = 0.f;
        for (int cc = 0; cc < C_; cc += 16) {
            __syncthreads();
#pragma unroll
            for (int j = 0; j < 2; ++j) {
                int f = tid + 256 * j;
                int cl = f >> 5;
                int t4 = (f & 31) * 4;
                float4 v = *(const float4*)(xbase + (size_t)(cc + cl) * T_ + t4);
                *(float4*)&Xs[cl * 128 + t4] = v;
            }
#pragma unroll
            for (int j = 0; j < 2; ++j) {
                int f = tid + 256 * j;
                int kl = f >> 2;
                int c4 = (f & 3) * 4;
                float4 v = *(const float4*)(cb + (size_t)(k0 + kl) * C_ + cc + c4);
                Bs[(c4 + 0) * 132 + kl] = v.x;
                Bs[(c4 + 1) * 132 + kl] = v.y;
                Bs[(c4 + 2) * 132 + kl] = v.z;
                Bs[(c4 + 3) * 132 + kl] = v.w;
            }
            __syncthreads();
#pragma unroll
            for (int c = 0; c < 16; ++c) {
                float4 xa = *(const float4*)&Xs[c * 128 + ty * 8];
                float4 xb2 = *(const float4*)&Xs[c * 128 + ty * 8 + 4];
                float4 ba = *(const float4*)&Bs[c * 132 + tx * 8];
                float4 bb = *(const float4*)&Bs[c * 132 + tx * 8 + 4];
                float xr[8] = {xa.x, xa.y, xa.z, xa.w, xb2.x, xb2.y, xb2.z, xb2.w};
                float br[8] = {ba.x, ba.y, ba.z, ba.w, bb.x, bb.y, bb.z, bb.w};
#pragma unroll
                for (int i = 0; i < 8; ++i)
#pragma unroll
                    for (int j = 0; j < 8; ++j)
                        acc[i][j] = fmaf(xr[i], br[j], acc[i][j]);
            }
        }
#pragma unroll
        for (int j = 0; j < 8; ++j) {
            const int kk = k0 + tx * 8 + j;
            const float kn = kns[tx * 8 + j];
#pragma unroll
            for (int i = 0; i < 8; ++i) {
                float s = fmaf(-2.f, acc[i][j], kn);
                if (s < best[i]) { best[i] = s; bestk[i] = kk; }
            }
        }
        __syncthreads();
    }
#pragma unroll
    for (int i = 0; i < 8; ++i) {
        redv[(ty * 8 + i) * 16 + tx] = best[i];
        redk[(ty * 8 + i) * 16 + tx] = bestk[i];
    }
    __syncthreads();
    if (tid < 128) {
        float bv = redv[tid * 16];
        int bk = redk[tid * 16];
#pragma unroll
        for (int j = 1; j < 16; ++j) {
            float v = redv[tid * 16 + j];
            int kj = redk[tid * 16 + j];
            if (v < bv || (v == bv && kj < bk)) { bv = v; bk = kj; }
        }
        idxs[tid] = bk;
    }
    __syncthreads();
    const int tg = (tid & 31) * 4;
    const int cs = tid >> 5;
    const float* r0 = cb + (size_t)idxs[tg + 0] * C_;
    const float* r1 = cb + (size_t)idxs[tg + 1] * C_;
    const float* r2 = cb + (size_t)idxs[tg + 2] * C_;
    const float* r3 = cb + (size_t)idxs[tg + 3] * C_;
    float* obase = out + (size_t)n * C_ * T_ + t0 + tg;
    for (int c = cs; c < C_; c += 8) {
        float4 v;
        v.x = r0[c]; v.y = r1[c]; v.z = r2[c]; v.w = r3[c];
        *(float4*)&obase[(size_t)c * T_] = v;
    }
}

extern "C" void kernel_launch(void* const* d_in, const int* in_sizes, int n_in,
                              void* d_out, int out_size, void* d_ws, size_t ws_size,
                              hipStream_t stream) {
    const float* x = (const float*)d_in[0];    // [32,512,2048] fp32
    const float* cb = (const float*)d_in[1];   // [1024,512] fp32
    float* out = (float*)d_out;
    char* ws = (char*)d_ws;

    if (ws_size < WS_NEED) {
        float* kn = (float*)ws;
        int* cnt0 = (int*)(ws + 4096);
        knorm_init_kernel<<<K_, 64, 0, stream>>>(cb, kn, out, cnt0);
        vq_fallback_kernel<<<(NT_) / 128, 256, 0, stream>>>(x, cb, kn, out);
        return;
    }

    f16* xws = (f16*)(ws + OFF_XH);
    f16* cbws = (f16*)(ws + OFF_CBH);
    float* knorm = (float*)(ws + OFF_KN);
    float4* top = (float4*)(ws + OFF_TOP);
    int* idx = (int*)(ws + OFF_IDX);
    int* cnt = (int*)(ws + OFF_CNT);
    int* list = (int*)(ws + OFF_LST);

    knorm_init_kernel<<<K_, 64, 0, stream>>>(cb, knorm, out, cnt);
    conv_cb_kernel<<<128, 256, 0, stream>>>(cb, cbws);
    conv_x_kernel<<<8192, 256, 0, stream>>>(x, xws);
    mfma_top2_kernel<<<4096, 256, 0, stream>>>(xws, cbws, knorm, top);
    combine_kernel<<<256, 256, 0, stream>>>(top, idx, cnt, list);
    rescan3_kernel<<<2048, 256, 0, stream>>>(x, cb, knorm, cnt, list, idx);
    gather2_kernel<<<512, 256, 0, stream>>>(cb, idx, out);
}